// Round 8
// baseline (157.181 us; speedup 1.0000x reference)
//
#include <hip/hip_runtime.h>
#include <cstdint>
#include <cstddef>

#define BSZ 16
#define LQ  512
#define HIDDIM 768
#define NH  12
#define HD  64
#define R2V 16
#define NTOT 1536   // fused N: K cols [0,768) | V cols [768,1536)
#define MTOT 8192   // BSZ*LQ

typedef __bf16 bf16x8 __attribute__((ext_vector_type(8)));
typedef float  f32x4  __attribute__((ext_vector_type(4)));

__device__ inline unsigned short f2bf(float x) {
    union { float f; unsigned u; } c; c.f = x;
    unsigned r = c.u + 0x7fffu + ((c.u >> 16) & 1u);   // RNE (no NaN here)
    return (unsigned short)(r >> 16);
}

// ---------------------------------------------------------------------------
// Kernel 0: cast hs + pack weights (K rows then V rows) to bf16; pack bias.
// ~45 MB traffic -> ~8 us. (Fused-cast attempts R5/R6 both regressed.)
// ---------------------------------------------------------------------------
#define NHS4 1572864   // 16*512*768/4
#define NW1  147456    // 768*768/4
#define NW4  294912    // 2*768*768/4

__global__ __launch_bounds__(256) void cast_pack(
    const float* __restrict__ hs,
    const float* __restrict__ Kw, const float* __restrict__ Vw,
    const float* __restrict__ Kb, const float* __restrict__ Vb,
    unsigned short* __restrict__ hsb, unsigned short* __restrict__ Wb,
    float* __restrict__ biasp)
{
    const int i = blockIdx.x * 256 + threadIdx.x;
    float4 v; unsigned short* dst;
    if (i < NHS4) {
        v = ((const float4*)hs)[i];
        dst = hsb + (size_t)i * 4;
    } else {
        const int j = i - NHS4;
        v = (j < NW1) ? ((const float4*)Kw)[j] : ((const float4*)Vw)[j - NW1];
        dst = Wb + (size_t)j * 4;
    }
    ushort4 o;
    o.x = f2bf(v.x); o.y = f2bf(v.y); o.z = f2bf(v.z); o.w = f2bf(v.w);
    *(ushort4*)dst = o;
    if (i < 768) { biasp[i] = Kb[i]; biasp[768 + i] = Vb[i]; }
}

// ---------------------------------------------------------------------------
// Kernel 1: bf16 MFMA GEMM, 128x128 tile (R4 config — best measured), BK=32,
// 256 threads = 4 waves (2x2 of 64x64 wave tiles), dbuf LDS (32 KB),
// one barrier per K-iter, global_load_lds width=16.
// K-half epilogue: NO K1 materialization — each wave's 64-n span is exactly
// one head, so score[m,h] = sum_d relu(acc+bias)*rh[h,d] is computed in-
// register (16 FMA/mi + shfl_xor(16,32)) and written to scores[h][m] (393 KB).
// V-half epilogue: fp32 relu(acc+bias) -> V1f (write BW free per R3).
// Swapped-operand MFMA -> C^T layout (lane: m=lane&15, n=(lane>>4)*4+r).
// ---------------------------------------------------------------------------
#define TBM 128
#define TBN 128
#define TBK 32
#define KITERS (HIDDIM / TBK)   // 24

#define GLD16(g, l) __builtin_amdgcn_global_load_lds( \
    (const __attribute__((address_space(1))) void*)(g), \
    (__attribute__((address_space(3))) void*)(l), 16, 0, 0)

__global__ __launch_bounds__(256) void gemm_mfma(
    const unsigned short* __restrict__ Abf,   // 8192 x 768 bf16
    const unsigned short* __restrict__ Wbf,   // 1536 x 768 bf16
    const float* __restrict__ biasp,          // 1536 fp32
    const float* __restrict__ rh,             // 12 x 64 fp32
    float* __restrict__ scores,               // 12 x 8192 fp32 (h-major)
    float* __restrict__ V1f)                  // 8192 x 768 fp32
{
    __shared__ unsigned short As[2][TBM * TBK];  // 2 x 8 KB
    __shared__ unsigned short Bs[2][TBN * TBK];  // 2 x 8 KB

    const int n0   = blockIdx.x * TBN;
    const int m0   = blockIdx.y * TBM;
    const int tid  = threadIdx.x;
    const int wid  = tid >> 6;
    const int lane = tid & 63;
    const int wm   = (wid & 1) * 64;
    const int wn   = (wid >> 1) * 64;

    f32x4 acc[4][4] = {};   // lane: m=lane&15, n-quad=(lane>>4)*4 (C^T)

    // staging: wave wid covers rows [wid*32, wid*32+32) of each tile.
    const int r0 = wid * 32;
    const int rA = r0 + (lane >> 2);
    const int kp = (lane & 3) * 8;

    const unsigned short* Ap0 = Abf + (size_t)(m0 + rA) * HIDDIM + kp;
    const unsigned short* Ap1 = Abf + (size_t)(m0 + rA + 16) * HIDDIM + kp;
    const unsigned short* Bp0 = Wbf + (size_t)(n0 + rA) * HIDDIM + kp;
    const unsigned short* Bp1 = Wbf + (size_t)(n0 + rA + 16) * HIDDIM + kp;

#define STAGE(buf, kof)                                        \
    do {                                                       \
        GLD16(Ap0 + (kof), &As[buf][r0 * TBK]);                \
        GLD16(Ap1 + (kof), &As[buf][(r0 + 16) * TBK]);         \
        GLD16(Bp0 + (kof), &Bs[buf][r0 * TBK]);                \
        GLD16(Bp1 + (kof), &Bs[buf][(r0 + 16) * TBK]);         \
    } while (0)

    const int fm = lane & 15;
    const int fk = (lane >> 4) * 8;

    STAGE(0, 0);   // prologue

    for (int it = 0; it < KITERS; ++it) {
        __syncthreads();   // drains stage(it) vmcnt + protects other-buf reuse
        const int cb = it & 1;
        if (it + 1 < KITERS) STAGE(cb ^ 1, (it + 1) * TBK);

        bf16x8 af[4], bfr[4];
        #pragma unroll
        for (int mi = 0; mi < 4; ++mi)
            af[mi] = *reinterpret_cast<const bf16x8*>(&As[cb][(wm + mi * 16 + fm) * TBK + fk]);
        #pragma unroll
        for (int ni = 0; ni < 4; ++ni)
            bfr[ni] = *reinterpret_cast<const bf16x8*>(&Bs[cb][(wn + ni * 16 + fm) * TBK + fk]);
        #pragma unroll
        for (int mi = 0; mi < 4; ++mi)
            #pragma unroll
            for (int ni = 0; ni < 4; ++ni)
                acc[mi][ni] = __builtin_amdgcn_mfma_f32_16x16x32_bf16(
                    bfr[ni], af[mi], acc[mi][ni], 0, 0, 0);   // swapped: C^T
    }
#undef STAGE

    const bool isK = (n0 < HIDDIM);
    const int mloc = lane & 15;
    const int nq   = (lane >> 4) * 4;

    if (isK) {
        // ---- fused score epilogue: this wave's n-span == head h ----
        const int h = (n0 + wn) >> 6;               // 0..11
        float4 rhv[4], bvv[4];
        #pragma unroll
        for (int ni = 0; ni < 4; ++ni) {
            rhv[ni] = *(const float4*)(rh + h * HD + ni * 16 + nq);
            bvv[ni] = *(const float4*)(biasp + n0 + wn + ni * 16 + nq);
        }
        #pragma unroll
        for (int mi = 0; mi < 4; ++mi) {
            float s = 0.f;
            #pragma unroll
            for (int ni = 0; ni < 4; ++ni) {
                f32x4 a = acc[mi][ni];
                s += fmaxf(a[0] + bvv[ni].x, 0.f) * rhv[ni].x
                   + fmaxf(a[1] + bvv[ni].y, 0.f) * rhv[ni].y
                   + fmaxf(a[2] + bvv[ni].z, 0.f) * rhv[ni].z
                   + fmaxf(a[3] + bvv[ni].w, 0.f) * rhv[ni].w;
            }
            s += __shfl_xor(s, 16);
            s += __shfl_xor(s, 32);
            if (lane < 16)
                scores[(size_t)h * MTOT + m0 + wm + mi * 16 + lane] = s;
        }
    } else {
        const int ncol0 = n0 - HIDDIM;
        #pragma unroll
        for (int mi = 0; mi < 4; ++mi) {
            const int mg = m0 + wm + mi * 16 + mloc;
            #pragma unroll
            for (int ni = 0; ni < 4; ++ni) {
                const int col = ncol0 + wn + ni * 16 + nq;
                float4 bv = *(const float4*)(biasp + HIDDIM + col);
                f32x4 a = acc[mi][ni];
                float4 o;
                o.x = fmaxf(a[0] + bv.x, 0.f);
                o.y = fmaxf(a[1] + bv.y, 0.f);
                o.z = fmaxf(a[2] + bv.z, 0.f);
                o.w = fmaxf(a[3] + bv.w, 0.f);
                *(float4*)(V1f + (size_t)mg * HIDDIM + col) = o;
            }
        }
    }
}

// ---------------------------------------------------------------------------
// Kernel 2: fused per (b,h): score load -> softmax(+exp(-m)) -> events ->
// scans -> idx (LDS) -> gather from V1f -> out. 512 thr = 8 waves; 192 blocks.
// ---------------------------------------------------------------------------
#define SINF (1 << 30)
#define IXP 17   // idxs row stride (pad 16->17)

__global__ __launch_bounds__(512) void scan_gather(
    const float* __restrict__ scores,
    const float* __restrict__ V1f,
    const float* __restrict__ bw,
    float* __restrict__ out)
{
    const int bh   = blockIdx.x;       // 0..191
    const int b    = bh / NH;
    const int h    = bh % NH;
    const int l    = threadIdx.x;      // 0..511
    const int lane = l & 63;
    const int wid  = l >> 6;

    __shared__ float wredA[8];
    __shared__ float wredB[8];
    __shared__ int   wp0[8];
    __shared__ int   wp1[8];
    __shared__ int   wp2[8];
    __shared__ int   ev[LQ];
    __shared__ int   col0[LQ];
    __shared__ int   col1[LQ];
    __shared__ int   E[LQ];
    __shared__ int   idxs[LQ * IXP];   // ~34.8 KB
    __shared__ float wsm[R2V];

    if (l < R2V) wsm[l] = bw[h * R2V + l];

    // ---- 1. score: precomputed in gemm epilogue (coalesced load) ----
    const float s = scores[(size_t)h * MTOT + b * LQ + l];

    // ---- 2. max reduce ----
    float mx = s;
    #pragma unroll
    for (int off = 32; off > 0; off >>= 1) mx = fmaxf(mx, __shfl_xor(mx, off));
    if (lane == 0) wredA[wid] = mx;
    __syncthreads();
    float m = wredA[0];
    #pragma unroll
    for (int i = 1; i < 8; ++i) m = fmaxf(m, wredA[i]);

    // ---- 3. sum reduce ----
    const float e = expf(s - m);
    float sm = e;
    #pragma unroll
    for (int off = 32; off > 0; off >>= 1) sm += __shfl_xor(sm, off);
    if (lane == 0) wredB[wid] = sm;
    __syncthreads();
    float ssum = 0.f;
    #pragma unroll
    for (int i = 0; i < 8; ++i) ssum += wredB[i];

    const float p = e / ssum + expf(-m);
    const int event = (p > (1.5f / 512.0f)) ? 1 : 0;
    ev[l] = event;

    // ---- 4. col0: inclusive max-scan of (event ? l : -1) ----
    int v = event ? l : -1;
    #pragma unroll
    for (int off = 1; off < 64; off <<= 1) {
        int u = __shfl_up(v, off);
        if (lane >= off) v = (u > v) ? u : v;
    }
    if (lane == 63) wp0[wid] = v;
    __syncthreads();                     // ev + wp0 visible
    int pfx = -1;
    for (int i = 0; i < wid; ++i) pfx = (wp0[i] > pfx) ? wp0[i] : pfx;
    v = (pfx > v) ? pfx : v;
    col0[l] = (v >= 0) ? v : l;

    // ---- 5. col1: suffix min-scan of (ev[(l+1)&511] ? l : INF) ----
    int v1 = ev[(l + 1) & (LQ - 1)] ? l : SINF;
    #pragma unroll
    for (int off = 1; off < 64; off <<= 1) {
        int u = __shfl_down(v1, off);
        if (lane < 64 - off) v1 = (u < v1) ? u : v1;
    }
    if (lane == 0) wp1[wid] = v1;
    __syncthreads();
    int sfx = SINF;
    for (int i = wid + 1; i < 8; ++i) sfx = (wp1[i] < sfx) ? wp1[i] : sfx;
    v1 = (sfx < v1) ? sfx : v1;
    col1[l] = (l == 0) ? 0 : (((v1 < SINF) ? v1 : l) + 1);

    // ---- 6. prefix count of events over steps 1..l ----
    int c = (l >= 1) ? event : 0;
    #pragma unroll
    for (int off = 1; off < 64; off <<= 1) {
        int u = __shfl_up(c, off);
        if (lane >= off) c += u;
    }
    if (lane == 63) wp2[wid] = c;
    __syncthreads();
    for (int i = 0; i < wid; ++i) c += wp2[i];

    // ---- 7. event-time list ----
    if (l >= 1 && event) E[c - 1] = l;
    __syncthreads();                     // E, col0, col1 ready

    // ---- 8. idx registers -> LDS ----
    int* op = &idxs[l * IXP];
    #pragma unroll
    for (int j = 0; j < 8; ++j) {
        const int k = c - 1 - j;
        int f = 0, bb = 0;
        if (k >= 0) {
            const int t = E[k];          // t >= 1
            f  = col0[t - 1];
            bb = col1[t - 1];
        }
        op[2 * j]     = min(max(f, 0), LQ - 1);
        op[2 * j + 1] = min(max(bb, 0), LQ - 1);
    }
    __syncthreads();                     // idxs + wsm ready

    // ---- 9. gather: 8 lanes per l (dsl covers 8 d's), 8 rounds, 4-chunked ----
    const int dsl = lane & 7;
    const size_t vbase = (size_t)b * LQ * HIDDIM + h * HD + dsl * 8;

    for (int round = 0; round < 8; ++round) {
        const int lg = round * 64 + wid * 8 + (lane >> 3);
        const int* ip = &idxs[lg * IXP];
        float4 accA = make_float4(0.f, 0.f, 0.f, 0.f);
        float4 accB = make_float4(0.f, 0.f, 0.f, 0.f);
        #pragma unroll 1
        for (int rc = 0; rc < R2V; rc += 4) {
            const int i0 = ip[rc], i1 = ip[rc + 1], i2 = ip[rc + 2], i3 = ip[rc + 3];
            const float w0 = wsm[rc], w1 = wsm[rc + 1], w2 = wsm[rc + 2], w3 = wsm[rc + 3];
            const float* p0 = V1f + vbase + (size_t)i0 * HIDDIM;
            const float* p1 = V1f + vbase + (size_t)i1 * HIDDIM;
            const float* p2 = V1f + vbase + (size_t)i2 * HIDDIM;
            const float* p3 = V1f + vbase + (size_t)i3 * HIDDIM;
            float4 a0 = *(const float4*)p0, b0 = *(const float4*)(p0 + 4);
            float4 a1 = *(const float4*)p1, b1 = *(const float4*)(p1 + 4);
            float4 a2 = *(const float4*)p2, b2 = *(const float4*)(p2 + 4);
            float4 a3 = *(const float4*)p3, b3 = *(const float4*)(p3 + 4);
            accA.x += w0 * a0.x + w1 * a1.x + w2 * a2.x + w3 * a3.x;
            accA.y += w0 * a0.y + w1 * a1.y + w2 * a2.y + w3 * a3.y;
            accA.z += w0 * a0.z + w1 * a1.z + w2 * a2.z + w3 * a3.z;
            accA.w += w0 * a0.w + w1 * a1.w + w2 * a2.w + w3 * a3.w;
            accB.x += w0 * b0.x + w1 * b1.x + w2 * b2.x + w3 * b3.x;
            accB.y += w0 * b0.y + w1 * b1.y + w2 * b2.y + w3 * b3.y;
            accB.z += w0 * b0.z + w1 * b1.z + w2 * b2.z + w3 * b3.z;
            accB.w += w0 * b0.w + w1 * b1.w + w2 * b2.w + w3 * b3.w;
        }
        float* po = out + ((size_t)(b * LQ + lg) * NH + h) * HD + dsl * 8;
        *(float4*)po       = accA;
        *((float4*)po + 1) = accB;
    }
}

// ---------------------------------------------------------------------------
extern "C" void kernel_launch(void* const* d_in, const int* in_sizes, int n_in,
                              void* d_out, int out_size, void* d_ws, size_t ws_size,
                              hipStream_t stream)
{
    (void)in_sizes; (void)n_in; (void)out_size; (void)ws_size;

    const float* hs = (const float*)d_in[0];
    const float* Kw = (const float*)d_in[1];
    const float* Kb = (const float*)d_in[2];
    const float* Vw = (const float*)d_in[3];
    const float* Vb = (const float*)d_in[4];
    const float* rh = (const float*)d_in[5];
    const float* bw = (const float*)d_in[6];
    float* out = (float*)d_out;

    // ws layout (bytes):
    //   V1f    fp32 8192*768  @ 0         (25.17 MB)
    //   hsb    bf16 8192*768  @ 25165824  (12.58 MB)
    //   Wb     bf16 1536*768  @ 37748736  ( 2.36 MB)
    //   biasp  fp32 1536      @ 40108032  ( 6 KB)
    //   scores fp32 12*8192   @ 40114176  ( 393 KB)
    char* ws = (char*)d_ws;
    float*          V1f    = (float*)(ws);
    unsigned short* hsb    = (unsigned short*)(ws + 25165824);
    unsigned short* Wb     = (unsigned short*)(ws + 37748736);
    float*          biasp  = (float*)(ws + 40108032);
    float*          scores = (float*)(ws + 40114176);

    cast_pack<<<(NHS4 + NW4) / 256, 256, 0, stream>>>(hs, Kw, Vw, Kb, Vb, hsb, Wb, biasp);

    dim3 g1(NTOT / TBN, MTOT / TBM);   // 12 x 64 = 768 blocks
    gemm_mfma<<<g1, 256, 0, stream>>>(hsb, Wb, biasp, rh, scores, V1f);

    scan_gather<<<BSZ * NH, LQ, 0, stream>>>(scores, V1f, bw, out);
}

// Round 9
// 145.899 us; speedup vs baseline: 1.0773x; 1.0773x over previous
//
#include <hip/hip_runtime.h>
#include <cstdint>
#include <cstddef>

#define BSZ 16
#define LQ  512
#define HIDDIM 768
#define NH  12
#define HD  64
#define R2V 16
#define NTOT 1536   // fused N: K cols [0,768) | V cols [768,1536)
#define MTOT 8192   // BSZ*LQ

typedef __bf16 bf16x8 __attribute__((ext_vector_type(8)));
typedef float  f32x4  __attribute__((ext_vector_type(4)));

__device__ inline unsigned short f2bf(float x) {
    union { float f; unsigned u; } c; c.f = x;
    unsigned r = c.u + 0x7fffu + ((c.u >> 16) & 1u);   // RNE (no NaN here)
    return (unsigned short)(r >> 16);
}
__device__ inline float bfl(unsigned u) { return __uint_as_float(u << 16); }
__device__ inline float bfh(unsigned u) { return __uint_as_float(u & 0xffff0000u); }

// ---------------------------------------------------------------------------
// Kernel 0: cast hs + pack weights (K rows then V rows) to bf16; pack bias.
// (R4 structure — measured best. Fused-cast variants R5/R6 regressed;
//  score-fused epilogue R8 regressed; tile changes R7 regressed.)
// ---------------------------------------------------------------------------
#define NHS4 1572864   // 16*512*768/4
#define NW1  147456    // 768*768/4
#define NW4  294912    // 2*768*768/4

__global__ __launch_bounds__(256) void cast_pack(
    const float* __restrict__ hs,
    const float* __restrict__ Kw, const float* __restrict__ Vw,
    const float* __restrict__ Kb, const float* __restrict__ Vb,
    unsigned short* __restrict__ hsb, unsigned short* __restrict__ Wb,
    float* __restrict__ biasp)
{
    const int i = blockIdx.x * 256 + threadIdx.x;
    float4 v; unsigned short* dst;
    if (i < NHS4) {
        v = ((const float4*)hs)[i];
        dst = hsb + (size_t)i * 4;
    } else {
        const int j = i - NHS4;
        v = (j < NW1) ? ((const float4*)Kw)[j] : ((const float4*)Vw)[j - NW1];
        dst = Wb + (size_t)j * 4;
    }
    ushort4 o;
    o.x = f2bf(v.x); o.y = f2bf(v.y); o.z = f2bf(v.z); o.w = f2bf(v.w);
    *(ushort4*)dst = o;
    if (i < 768) { biasp[i] = Kb[i]; biasp[768 + i] = Vb[i]; }
}

// ---------------------------------------------------------------------------
// Kernel 1: bf16 MFMA GEMM -> bf16 outputs. (R4 exact — measured best.)
// 128x128 tile, BK=32, 256 threads = 4 waves, 16x16x32 MFMA.
// DOUBLE-BUFFERED LDS, one barrier per K-iter: the barrier at iter t drains
// the global_load_lds issued at iter t-1 (which overlapped iter t-1's MFMAs).
// Swapped-operand MFMA -> C^T layout -> ushort4 stores.
// ---------------------------------------------------------------------------
#define TBM 128
#define TBN 128
#define TBK 32
#define KITERS (HIDDIM / TBK)   // 24

#define GLD16(g, l) __builtin_amdgcn_global_load_lds( \
    (const __attribute__((address_space(1))) void*)(g), \
    (__attribute__((address_space(3))) void*)(l), 16, 0, 0)

__global__ __launch_bounds__(256) void gemm_mfma(
    const unsigned short* __restrict__ Abf,   // 8192 x 768 bf16
    const unsigned short* __restrict__ Wbf,   // 1536 x 768 bf16
    const float* __restrict__ biasp,          // 1536 fp32
    unsigned short* __restrict__ K1b, unsigned short* __restrict__ V1b)
{
    __shared__ unsigned short As[2][TBM * TBK];  // 2 x 8 KB
    __shared__ unsigned short Bs[2][TBN * TBK];  // 2 x 8 KB

    const int n0   = blockIdx.x * TBN;
    const int m0   = blockIdx.y * TBM;
    const int tid  = threadIdx.x;
    const int wid  = tid >> 6;
    const int lane = tid & 63;
    const int wm   = (wid & 1) * 64;
    const int wn   = (wid >> 1) * 64;

    f32x4 acc[4][4] = {};   // lane holds m=lane&15, n-quad=(lane>>4)*4 (C^T)

    // staging: wave wid covers rows [wid*32, wid*32+32) of each tile.
    // one GLD16: 64 lanes x 16B = 16 rows (row = lane/4, kpart = (lane%4)*8)
    const int r0 = wid * 32;
    const int rA = r0 + (lane >> 2);
    const int kp = (lane & 3) * 8;

    const unsigned short* Ap0 = Abf + (size_t)(m0 + rA) * HIDDIM + kp;
    const unsigned short* Ap1 = Abf + (size_t)(m0 + rA + 16) * HIDDIM + kp;
    const unsigned short* Bp0 = Wbf + (size_t)(n0 + rA) * HIDDIM + kp;
    const unsigned short* Bp1 = Wbf + (size_t)(n0 + rA + 16) * HIDDIM + kp;

    const int fm = lane & 15;
    const int fk = (lane >> 4) * 8;

#define STAGE(buf, kof)                                        \
    do {                                                       \
        GLD16(Ap0 + (kof), &As[buf][r0 * TBK]);                \
        GLD16(Ap1 + (kof), &As[buf][(r0 + 16) * TBK]);         \
        GLD16(Bp0 + (kof), &Bs[buf][r0 * TBK]);                \
        GLD16(Bp1 + (kof), &Bs[buf][(r0 + 16) * TBK]);         \
    } while (0)

    STAGE(0, 0);   // prologue: stage tile 0 into buf 0

    for (int it = 0; it < KITERS; ++it) {
        __syncthreads();   // drains stage(it) [vmcnt] + protects LDS reuse
        if (it + 1 < KITERS) STAGE((it + 1) & 1, (it + 1) * TBK);
        const int cb = it & 1;

        bf16x8 af[4], bfr[4];
        #pragma unroll
        for (int mi = 0; mi < 4; ++mi)
            af[mi] = *reinterpret_cast<const bf16x8*>(&As[cb][(wm + mi * 16 + fm) * TBK + fk]);
        #pragma unroll
        for (int ni = 0; ni < 4; ++ni)
            bfr[ni] = *reinterpret_cast<const bf16x8*>(&Bs[cb][(wn + ni * 16 + fm) * TBK + fk]);
        #pragma unroll
        for (int mi = 0; mi < 4; ++mi)
            #pragma unroll
            for (int ni = 0; ni < 4; ++ni)
                acc[mi][ni] = __builtin_amdgcn_mfma_f32_16x16x32_bf16(
                    bfr[ni], af[mi], acc[mi][ni], 0, 0, 0);   // swapped: C^T
    }
#undef STAGE

    // epilogue: lane holds m = lane&15, n = (lane>>4)*4 + r (4 consecutive)
    const bool isK = (n0 < HIDDIM);
    unsigned short* __restrict__ dst = isK ? K1b : V1b;
    const int nsub = isK ? 0 : HIDDIM;
    const int mloc = lane & 15;
    const int nq   = (lane >> 4) * 4;

    #pragma unroll
    for (int mi = 0; mi < 4; ++mi) {
        const int mg = m0 + wm + mi * 16 + mloc;
        #pragma unroll
        for (int ni = 0; ni < 4; ++ni) {
            const int ng = n0 + wn + ni * 16 + nq;
            float4 bv = *(const float4*)(biasp + ng);
            f32x4 a = acc[mi][ni];
            ushort4 o;
            o.x = f2bf(fmaxf(a[0] + bv.x, 0.f));
            o.y = f2bf(fmaxf(a[1] + bv.y, 0.f));
            o.z = f2bf(fmaxf(a[2] + bv.z, 0.f));
            o.w = f2bf(fmaxf(a[3] + bv.w, 0.f));
            *(ushort4*)(dst + (size_t)mg * HIDDIM + (ng - nsub)) = o;
        }
    }
}

// ---------------------------------------------------------------------------
// Kernel 2: fused per (b,h): scores -> softmax(+exp(-m)) -> events -> scans
// -> idx (LDS) -> gather from V1b -> out.  512 threads = 8 waves; 192 blocks.
// Gather chunked 4-deep (unroll 1 on chunk loop) to cap VGPR pressure.
// ---------------------------------------------------------------------------
#define SINF (1 << 30)
#define IXP 17   // idxs row stride (pad 16->17)

__global__ __launch_bounds__(512) void scan_gather(
    const unsigned short* __restrict__ K1b,
    const unsigned short* __restrict__ V1b,
    const float* __restrict__ rh,
    const float* __restrict__ bw,
    float* __restrict__ out)
{
    const int bh   = blockIdx.x;       // 0..191
    const int b    = bh / NH;
    const int h    = bh % NH;
    const int l    = threadIdx.x;      // 0..511
    const int lane = l & 63;
    const int wid  = l >> 6;

    __shared__ float wredA[8];
    __shared__ float wredB[8];
    __shared__ int   wp0[8];
    __shared__ int   wp1[8];
    __shared__ int   wp2[8];
    __shared__ int   ev[LQ];
    __shared__ int   col0[LQ];
    __shared__ int   col1[LQ];
    __shared__ int   E[LQ];
    __shared__ int   idxs[LQ * IXP];   // ~34.8 KB
    __shared__ float wsm[R2V];

    if (l < R2V) wsm[l] = bw[h * R2V + l];

    // ---- 1. score: dot64(bf16 K1 row, fp32 reading_head) ----
    const unsigned short* krow = K1b + ((size_t)(b * LQ + l)) * HIDDIM + h * HD;
    const float* rrow = rh + h * HD;
    float s = 0.f;
    #pragma unroll
    for (int c8 = 0; c8 < 8; ++c8) {
        uint4 kv = *(const uint4*)(krow + c8 * 8);
        float4 ra = *(const float4*)(rrow + c8 * 8);
        float4 rb = *(const float4*)(rrow + c8 * 8 + 4);
        s += bfl(kv.x) * ra.x + bfh(kv.x) * ra.y
           + bfl(kv.y) * ra.z + bfh(kv.y) * ra.w
           + bfl(kv.z) * rb.x + bfh(kv.z) * rb.y
           + bfl(kv.w) * rb.z + bfh(kv.w) * rb.w;
    }

    // ---- 2. max reduce ----
    float mx = s;
    #pragma unroll
    for (int off = 32; off > 0; off >>= 1) mx = fmaxf(mx, __shfl_xor(mx, off));
    if (lane == 0) wredA[wid] = mx;
    __syncthreads();
    float m = wredA[0];
    #pragma unroll
    for (int i = 1; i < 8; ++i) m = fmaxf(m, wredA[i]);

    // ---- 3. sum reduce ----
    const float e = expf(s - m);
    float sm = e;
    #pragma unroll
    for (int off = 32; off > 0; off >>= 1) sm += __shfl_xor(sm, off);
    if (lane == 0) wredB[wid] = sm;
    __syncthreads();
    float ssum = 0.f;
    #pragma unroll
    for (int i = 0; i < 8; ++i) ssum += wredB[i];

    const float p = e / ssum + expf(-m);
    const int event = (p > (1.5f / 512.0f)) ? 1 : 0;
    ev[l] = event;

    // ---- 4. col0: inclusive max-scan of (event ? l : -1) ----
    int v = event ? l : -1;
    #pragma unroll
    for (int off = 1; off < 64; off <<= 1) {
        int u = __shfl_up(v, off);
        if (lane >= off) v = (u > v) ? u : v;
    }
    if (lane == 63) wp0[wid] = v;
    __syncthreads();                     // ev + wp0 visible
    int pfx = -1;
    for (int i = 0; i < wid; ++i) pfx = (wp0[i] > pfx) ? wp0[i] : pfx;
    v = (pfx > v) ? pfx : v;
    col0[l] = (v >= 0) ? v : l;

    // ---- 5. col1: suffix min-scan of (ev[(l+1)&511] ? l : INF) ----
    int v1 = ev[(l + 1) & (LQ - 1)] ? l : SINF;
    #pragma unroll
    for (int off = 1; off < 64; off <<= 1) {
        int u = __shfl_down(v1, off);
        if (lane < 64 - off) v1 = (u < v1) ? u : v1;
    }
    if (lane == 0) wp1[wid] = v1;
    __syncthreads();
    int sfx = SINF;
    for (int i = wid + 1; i < 8; ++i) sfx = (wp1[i] < sfx) ? wp1[i] : sfx;
    v1 = (sfx < v1) ? sfx : v1;
    col1[l] = (l == 0) ? 0 : (((v1 < SINF) ? v1 : l) + 1);

    // ---- 6. prefix count of events over steps 1..l ----
    int c = (l >= 1) ? event : 0;
    #pragma unroll
    for (int off = 1; off < 64; off <<= 1) {
        int u = __shfl_up(c, off);
        if (lane >= off) c += u;
    }
    if (lane == 63) wp2[wid] = c;
    __syncthreads();
    for (int i = 0; i < wid; ++i) c += wp2[i];

    // ---- 7. event-time list ----
    if (l >= 1 && event) E[c - 1] = l;
    __syncthreads();                     // E, col0, col1 ready

    // ---- 8. idx registers -> LDS ----
    int* op = &idxs[l * IXP];
    #pragma unroll
    for (int j = 0; j < 8; ++j) {
        const int k = c - 1 - j;
        int f = 0, bb = 0;
        if (k >= 0) {
            const int t = E[k];          // t >= 1
            f  = col0[t - 1];
            bb = col1[t - 1];
        }
        op[2 * j]     = min(max(f, 0), LQ - 1);
        op[2 * j + 1] = min(max(bb, 0), LQ - 1);
    }
    __syncthreads();                     // idxs + wsm ready

    // ---- 9. gather: 8 lanes per l (dsl covers 8 d's), 8 rounds, 4-chunked ----
    const int dsl = lane & 7;
    const size_t vbase = (size_t)b * LQ * HIDDIM + h * HD + dsl * 8;

    for (int round = 0; round < 8; ++round) {
        const int lg = round * 64 + wid * 8 + (lane >> 3);
        const int* ip = &idxs[lg * IXP];
        float a0 = 0.f, a1 = 0.f, a2 = 0.f, a3 = 0.f;
        float a4 = 0.f, a5 = 0.f, a6 = 0.f, a7 = 0.f;
        #pragma unroll 1
        for (int rc = 0; rc < R2V; rc += 4) {
            const int i0 = ip[rc], i1 = ip[rc + 1], i2 = ip[rc + 2], i3 = ip[rc + 3];
            uint4 v0 = *(const uint4*)(V1b + vbase + (size_t)i0 * HIDDIM);
            uint4 vA = *(const uint4*)(V1b + vbase + (size_t)i1 * HIDDIM);
            uint4 vB = *(const uint4*)(V1b + vbase + (size_t)i2 * HIDDIM);
            uint4 vC = *(const uint4*)(V1b + vbase + (size_t)i3 * HIDDIM);
            const float w0 = wsm[rc], w1 = wsm[rc + 1], w2 = wsm[rc + 2], w3 = wsm[rc + 3];
            a0 += w0 * bfl(v0.x); a1 += w0 * bfh(v0.x);
            a2 += w0 * bfl(v0.y); a3 += w0 * bfh(v0.y);
            a4 += w0 * bfl(v0.z); a5 += w0 * bfh(v0.z);
            a6 += w0 * bfl(v0.w); a7 += w0 * bfh(v0.w);
            a0 += w1 * bfl(vA.x); a1 += w1 * bfh(vA.x);
            a2 += w1 * bfl(vA.y); a3 += w1 * bfh(vA.y);
            a4 += w1 * bfl(vA.z); a5 += w1 * bfh(vA.z);
            a6 += w1 * bfl(vA.w); a7 += w1 * bfh(vA.w);
            a0 += w2 * bfl(vB.x); a1 += w2 * bfh(vB.x);
            a2 += w2 * bfl(vB.y); a3 += w2 * bfh(vB.y);
            a4 += w2 * bfl(vB.z); a5 += w2 * bfh(vB.z);
            a6 += w2 * bfl(vB.w); a7 += w2 * bfh(vB.w);
            a0 += w3 * bfl(vC.x); a1 += w3 * bfh(vC.x);
            a2 += w3 * bfl(vC.y); a3 += w3 * bfh(vC.y);
            a4 += w3 * bfl(vC.z); a5 += w3 * bfh(vC.z);
            a6 += w3 * bfl(vC.w); a7 += w3 * bfh(vC.w);
        }
        float* po = out + ((size_t)(b * LQ + lg) * NH + h) * HD + dsl * 8;
        *(float4*)po       = make_float4(a0, a1, a2, a3);
        *((float4*)po + 1) = make_float4(a4, a5, a6, a7);
    }
}

// ---------------------------------------------------------------------------
extern "C" void kernel_launch(void* const* d_in, const int* in_sizes, int n_in,
                              void* d_out, int out_size, void* d_ws, size_t ws_size,
                              hipStream_t stream)
{
    (void)in_sizes; (void)n_in; (void)out_size; (void)ws_size;

    const float* hs = (const float*)d_in[0];
    const float* Kw = (const float*)d_in[1];
    const float* Kb = (const float*)d_in[2];
    const float* Vw = (const float*)d_in[3];
    const float* Vb = (const float*)d_in[4];
    const float* rh = (const float*)d_in[5];
    const float* bw = (const float*)d_in[6];
    float* out = (float*)d_out;

    // ws layout (bytes):
    //   K1b  bf16 8192*768  @ 0         (12.58 MB)
    //   V1b  bf16 8192*768  @ 12582912  (12.58 MB)
    //   hsb  bf16 8192*768  @ 25165824  (12.58 MB)
    //   Wb   bf16 1536*768  @ 37748736  ( 2.36 MB)
    //   bias fp32 1536      @ 40108032  ( 6 KB)
    char* ws = (char*)d_ws;
    unsigned short* K1b   = (unsigned short*)(ws);
    unsigned short* V1b   = (unsigned short*)(ws + 12582912);
    unsigned short* hsb   = (unsigned short*)(ws + 25165824);
    unsigned short* Wb    = (unsigned short*)(ws + 37748736);
    float*          biasp = (float*)(ws + 40108032);

    cast_pack<<<(NHS4 + NW4) / 256, 256, 0, stream>>>(hs, Kw, Vw, Kb, Vb, hsb, Wb, biasp);

    dim3 g1(NTOT / TBN, MTOT / TBM);   // 12 x 64
    gemm_mfma<<<g1, 256, 0, stream>>>(hsb, Wb, biasp, K1b, V1b);

    scan_gather<<<BSZ * NH, LQ, 0, stream>>>(K1b, V1b, rh, bw, out);
}